// Round 9
// baseline (64.134 us; speedup 1.0000x reference)
//
#include <hip/hip_runtime.h>
#include <math.h>

#define ALPHA_F 100.0f

constexpr int N_ = 32, C_ = 128, K_ = 64, S_ = 4096;
constexpr int NCHUNK = 16, SCHUNK = S_ / NCHUNK;  // 256
constexpr int ST = 128, NSUB = SCHUNK / ST;       // 2 subtiles of 128 pixels
constexpr int NT = 512;                           // 8 waves

typedef _Float16 f16;
typedef __attribute__((ext_vector_type(4))) _Float16 f16x4;
typedef __attribute__((ext_vector_type(8))) _Float16 f16x8;
typedef __attribute__((ext_vector_type(4))) float f32x4;

// LDS layout (bytes) — exactly 80 KiB so 2 blocks/CU fill the 160 KiB file.
// xbh: x fp16 [c=128][s=128], octet swizzle: u16 addr = c*128 + ((s>>3)^(c&15))*8 + (s&7)
// a_s: a' fp16 [k=64][s=128],  u16 addr = k*128 + ((s>>3)^(k&15))*8 + (s&7)
//      (f32 scr[4096] aliases this region pre-loop/epilogue)
// cls/chs: centroid lo / hi, ALL 64 rows each, octet^k swizzle (R6-validated)
constexpr int XBH = 0;        // 32768
constexpr int ASB = 32768;    // 16384
constexpr int CLS = 49152;    // 16384
constexpr int CHS = 65536;    // 16384
constexpr int LDS_SZ = 81920; // 2 * 81920 = 163840 = full LDS

#define BARRIER() do { asm volatile("s_waitcnt lgkmcnt(0)" ::: "memory"); \
                       __builtin_amdgcn_s_barrier(); } while (0)

__global__ __launch_bounds__(NT, 4)
void nv_stage1(const float* __restrict__ x, const float* __restrict__ cent,
               float* __restrict__ vlad_part, float* __restrict__ asum_part) {
  __shared__ __align__(16) unsigned char lds[LDS_SZ];
  ushort* xbh  = (ushort*)(lds + XBH);
  ushort* a_s  = (ushort*)(lds + ASB);
  float*  scr  = (float*)(lds + ASB);
  ushort* cls  = (ushort*)(lds + CLS);
  ushort* chs  = (ushort*)(lds + CHS);

  const int t = threadIdx.x;
  const int l = t & 63, w = t >> 6;
  const int l16 = l & 15, g = l >> 4;
  const int chunk = blockIdx.x, n = blockIdx.y;
  const int sb = w * 16, cb = w * 16;     // wave's s-tile (GEMM1) / c-tile (GEMM2)

  const float* xg = x + (size_t)n * C_ * S_ + (size_t)chunk * SCHUNK;
  const float* xcol0 = xg + sb + l16;     // lane's pixel column

  // ---- prologue: stage subtile 0 as hi/lo A-fragments (x read ONCE)
  f16x8 ah[4], al[4];
  float inv_cur;
  {
    float ss = 0.f;
    #pragma unroll
    for (int ks = 0; ks < 4; ++ks) {
      const float* p = xcol0 + (size_t)(ks * 32 + g * 8) * S_;
      #pragma unroll
      for (int j = 0; j < 8; ++j) {
        float v = p[(size_t)j * S_];
        ss += v * v;
        f16 h = (f16)v;
        ah[ks][j] = h;
        al[ks][j] = (f16)(v - (float)h);
      }
    }
    ss += __shfl_xor(ss, 16);
    ss += __shfl_xor(ss, 32);
    inv_cur = 1.0f / fmaxf(sqrtf(ss), 1e-12f);
  }

  // bias partials (k = l, c-range w*16..+16) -> scr[0..511]
  {
    const float* cr = cent + l * C_ + w * 16;
    float ss = 0.f;
    #pragma unroll
    for (int h = 0; h < 4; ++h) {
      float4 v = *(const float4*)(cr + h * 4);
      ss += v.x * v.x + v.y * v.y + v.z * v.z + v.w * v.w;
    }
    scr[w * 64 + l] = ss;
  }
  // cent-lo: k = t>>3, 16 c at (t&7)*16; lo = c - (float)hi   (R6-validated)
  {
    const int k = t >> 3, c7 = t & 7;
    const float* cr = cent + k * C_ + c7 * 16;
    f16x8 lo0, lo1;
    #pragma unroll
    for (int h = 0; h < 8; ++h) {
      float v0 = cr[h], v1 = cr[8 + h];
      lo0[h] = (f16)(v0 - (float)((f16)v0));
      lo1[h] = (f16)(v1 - (float)((f16)v1));
    }
    *(f16x8*)&cls[k * 128 + ((2 * c7) ^ (k & 15)) * 8]     = lo0;
    *(f16x8*)&cls[k * 128 + ((2 * c7 + 1) ^ (k & 15)) * 8] = lo1;
  }
  // cent-hi ALL rows k=0..63 -> chs (512 threads: one (row, c-octet-pair) each)
  {
    const int kl = t >> 3, c7 = t & 7;
    const float* cr = cent + kl * C_ + c7 * 16;
    f16x8 h0v, h1v;
    #pragma unroll
    for (int h = 0; h < 8; ++h) { h0v[h] = (f16)cr[h]; h1v[h] = (f16)cr[8 + h]; }
    *(f16x8*)&chs[kl * 128 + ((2 * c7) ^ (kl & 15)) * 8]     = h0v;
    *(f16x8*)&chs[kl * 128 + ((2 * c7 + 1) ^ (kl & 15)) * 8] = h1v;
  }
  __syncthreads();
  if (t < 64) {
    float ss = 0.f;
    #pragma unroll
    for (int q = 0; q < 8; ++q) ss += scr[q * 64 + t];
    scr[512 + t] = -ALPHA_F * sqrtf(ss);     // bias, transient
  }
  __syncthreads();
  float bias_r[4];
  #pragma unroll
  for (int nt2 = 0; nt2 < 4; ++nt2) bias_r[nt2] = scr[512 + nt2 * 16 + l16];
  __syncthreads();   // all waves read bias before a_s (same region) is overwritten

  f32x4 acc2[4];
  #pragma unroll
  for (int nt2 = 0; nt2 < 4; ++nt2) { f32x4 z = {0.f,0.f,0.f,0.f}; acc2[nt2] = z; }
  float asum_acc[4] = {0.f, 0.f, 0.f, 0.f};

  const int octP = sb + l16 >> 3;  // careful precedence fixed below
  const int sP   = sb + l16;

  for (int st = 0; st < NSUB; ++st) {
    // ---- P0: write xbh [c][s] (octet-swizzled) from A-frag regs
    {
      const int op = sP >> 3, s7 = sP & 7;
      union { f16x8 v; ushort u[8]; } cv;
      #pragma unroll
      for (int ks = 0; ks < 4; ++ks) {
        cv.v = ah[ks];
        #pragma unroll
        for (int j = 0; j < 8; ++j) {
          int c = ks * 32 + g * 8 + j;
          xbh[c * 128 + ((op ^ (c & 15)) << 3) + s7] = cv.u[j];
        }
      }
    }

    // ---- D: GEMM1 (ah*bh + ah*bl + al*bh); softmax; a' -> a_s
    {
      f32x4 acc1[4];
      #pragma unroll
      for (int nt2 = 0; nt2 < 4; ++nt2) { f32x4 z = {0.f,0.f,0.f,0.f}; acc1[nt2] = z; }
      #pragma unroll
      for (int ks = 0; ks < 4; ++ks) {
        #pragma unroll
        for (int nt2 = 0; nt2 < 4; ++nt2) {
          f16x8 bh = *(const f16x8*)&chs[(nt2 * 16 + l16) * 128 + (((ks * 4 + g) ^ l16) * 8)];
          f16x8 bl = *(const f16x8*)&cls[(nt2 * 16 + l16) * 128 + (((ks * 4 + g) ^ l16) * 8)];
          acc1[nt2] = __builtin_amdgcn_mfma_f32_16x16x32_f16(ah[ks], bh, acc1[nt2], 0, 0, 0);
          acc1[nt2] = __builtin_amdgcn_mfma_f32_16x16x32_f16(ah[ks], bl, acc1[nt2], 0, 0, 0);
          acc1[nt2] = __builtin_amdgcn_mfma_f32_16x16x32_f16(al[ks], bh, acc1[nt2], 0, 0, 0);
        }
      }
      // inv for D-row pixels s = sb + 4g + i: lane (4g+i) of this wave holds it
      float inv4[4];
      #pragma unroll
      for (int i = 0; i < 4; ++i) inv4[i] = __shfl(inv_cur, 4 * g + i, 64);
      float v[4][4], mx[4], sm[4];
      #pragma unroll
      for (int nt2 = 0; nt2 < 4; ++nt2)
        #pragma unroll
        for (int i = 0; i < 4; ++i)
          v[nt2][i] = 2.f * ALPHA_F * acc1[nt2][i] * inv4[i] + bias_r[nt2];
      #pragma unroll
      for (int i = 0; i < 4; ++i) {
        mx[i] = fmaxf(fmaxf(v[0][i], v[1][i]), fmaxf(v[2][i], v[3][i]));
        mx[i] = fmaxf(mx[i], __shfl_xor(mx[i], 1));
        mx[i] = fmaxf(mx[i], __shfl_xor(mx[i], 2));
        mx[i] = fmaxf(mx[i], __shfl_xor(mx[i], 4));
        mx[i] = fmaxf(mx[i], __shfl_xor(mx[i], 8));
        sm[i] = 0.f;
      }
      #pragma unroll
      for (int nt2 = 0; nt2 < 4; ++nt2)
        #pragma unroll
        for (int i = 0; i < 4; ++i) { float e = __expf(v[nt2][i] - mx[i]); v[nt2][i] = e; sm[i] += e; }
      #pragma unroll
      for (int i = 0; i < 4; ++i) {
        sm[i] += __shfl_xor(sm[i], 1); sm[i] += __shfl_xor(sm[i], 2);
        sm[i] += __shfl_xor(sm[i], 4); sm[i] += __shfl_xor(sm[i], 8);
        sm[i] = 1.0f / sm[i];
      }
      // a' write: k = nt2*16+l16, s-octet = 2w + (g>>1), s&7 base = 4*(g&1)
      const int oa = 2 * w + (g >> 1), pa4 = (g & 1) * 4;
      #pragma unroll
      for (int nt2 = 0; nt2 < 4; ++nt2) {
        float a0 = v[nt2][0] * sm[0], a1 = v[nt2][1] * sm[1];
        float a2 = v[nt2][2] * sm[2], a3 = v[nt2][3] * sm[3];
        asum_acc[nt2] += a0 + a1 + a2 + a3;
        f16x4 av;
        av[0] = (f16)(a0 * inv4[0]); av[1] = (f16)(a1 * inv4[1]);
        av[2] = (f16)(a2 * inv4[2]); av[3] = (f16)(a3 * inv4[3]);
        *(f16x4*)&a_s[(nt2 * 16 + l16) * 128 + ((oa ^ l16) << 3) + pa4] = av;
      }
    }
    BARRIER();  // xbh + a_s ready for all waves

    // ---- E: GEMM2 D[c][k] += x[c][s] . a'[k][s]  (R6-validated mapping)
    #pragma unroll
    for (int ks = 0; ks < 4; ++ks) {
      const int c2 = cb + l16;   // c&15 = l16
      f16x8 xu = *(const f16x8*)&xbh[c2 * 128 + (((ks * 4 + g) ^ l16) << 3)];
      #pragma unroll
      for (int nt2 = 0; nt2 < 4; ++nt2) {
        f16x8 pa = *(const f16x8*)&a_s[(nt2 * 16 + l16) * 128 + (((ks * 4 + g) ^ l16) << 3)];
        acc2[nt2] = __builtin_amdgcn_mfma_f32_16x16x32_f16(xu, pa, acc2[nt2], 0, 0, 0);
      }
    }
    // prefetch next subtile hi/lo A-frags, overlapped with MFMA drain
    if (st + 1 < NSUB) {
      const float* xc = xcol0 + (st + 1) * ST;
      float ss = 0.f;
      #pragma unroll
      for (int ks = 0; ks < 4; ++ks) {
        const float* p = xc + (size_t)(ks * 32 + g * 8) * S_;
        #pragma unroll
        for (int j = 0; j < 8; ++j) {
          float v = p[(size_t)j * S_];
          ss += v * v;
          f16 h = (f16)v;
          ah[ks][j] = h;
          al[ks][j] = (f16)(v - (float)h);
        }
      }
      ss += __shfl_xor(ss, 16);
      ss += __shfl_xor(ss, 32);
      inv_cur = 1.0f / fmaxf(sqrtf(ss), 1e-12f);
    }
    BARRIER();  // xbh/a_s consumed; safe to overwrite next iteration
  }

  // ---- epilogue: stage acc2 in quad-swizzled f32 [64][128] (xbh region) + asum
  {
    float* vst = (float*)(lds + XBH);
    #pragma unroll
    for (int nt2 = 0; nt2 < 4; ++nt2) {
      const int k = nt2 * 16 + l16, q = 4 * w + g;   // c-quad index
      float4 o = make_float4(acc2[nt2][0], acc2[nt2][1], acc2[nt2][2], acc2[nt2][3]);
      *(float4*)&vst[k * 128 + ((q ^ (k & 7)) << 2)] = o;
      float vv = asum_acc[nt2];
      vv += __shfl_xor(vv, 16); vv += __shfl_xor(vv, 32);
      if (g == 0) scr[w * 64 + nt2 * 16 + l16] = vv;
    }
    BARRIER();
    const size_t base = (size_t)(n * NCHUNK + chunk) * (K_ * C_);
    #pragma unroll
    for (int it = 0; it < 4; ++it) {
      int f = t + it * 512;              // float4 slot in [0,2048)
      int k = f >> 5, q = f & 31;
      float4 v = *(float4*)&vst[k * 128 + ((q ^ (k & 7)) << 2)];
      *(float4*)&vlad_part[base + (size_t)k * C_ + q * 4] = v;   // contiguous lines
    }
    if (t < 64) {
      float s2 = 0.f;
      #pragma unroll
      for (int q = 0; q < 8; ++q) s2 += scr[q * 64 + t];
      asum_part[(n * NCHUNK + chunk) * K_ + t] = s2;
    }
  }
}

// ---- stage 2a: reduce chunks, subtract, intra-normalize (256 blocks) ----
__global__ __launch_bounds__(256)
void nv_stage2a(const float* __restrict__ vlad_part, const float* __restrict__ asum_part,
                const float* __restrict__ cent, float* __restrict__ vlad_n,
                float* __restrict__ rssq) {
  const int t = threadIdx.x, b = blockIdx.x;
  const int n = b >> 3, k8 = (b & 7) * 8;
  const int kl = t >> 5, c4 = (t & 31) * 4;
  const int k = k8 + kl;
  float as = 0.f;
  for (int ch = 0; ch < NCHUNK; ++ch) as += asum_part[(n * NCHUNK + ch) * K_ + k];
  float4 acc = make_float4(0.f, 0.f, 0.f, 0.f);
  for (int ch = 0; ch < NCHUNK; ++ch) {
    float4 v = *(const float4*)&vlad_part[((size_t)(n * NCHUNK + ch) * K_ + k) * C_ + c4];
    acc.x += v.x; acc.y += v.y; acc.z += v.z; acc.w += v.w;
  }
  float4 cw = *(const float4*)&cent[k * C_ + c4];
  acc.x -= as * cw.x; acc.y -= as * cw.y; acc.z -= as * cw.z; acc.w -= as * cw.w;
  float ssq = acc.x * acc.x + acc.y * acc.y + acc.z * acc.z + acc.w * acc.w;
  #pragma unroll
  for (int m = 1; m <= 16; m <<= 1) ssq += __shfl_xor(ssq, m);
  float scl = 1.0f / fmaxf(sqrtf(ssq), 1e-12f);
  *(float4*)&vlad_n[(size_t)n * (K_ * C_) + k * C_ + c4] =
      make_float4(acc.x * scl, acc.y * scl, acc.z * scl, acc.w * scl);
  if ((t & 31) == 0) rssq[n * K_ + k] = ssq * scl * scl;
}

// ---- stage 2b: global L2 normalize (32 blocks) ----
__global__ __launch_bounds__(256)
void nv_stage2b(const float* __restrict__ vlad_n, const float* __restrict__ rssq,
                float* __restrict__ out) {
  const int t = threadIdx.x, n = blockIdx.x;
  float tot = 0.f;
  for (int k2 = 0; k2 < K_; ++k2) tot += rssq[n * K_ + k2];
  const float rfin = 1.0f / fmaxf(sqrtf(tot), 1e-12f);
  #pragma unroll
  for (int r = 0; r < 8; ++r) {
    int idx = t * 4 + r * 1024;
    float4 v = *(const float4*)&vlad_n[(size_t)n * (K_ * C_) + idx];
    *(float4*)&out[(size_t)n * (K_ * C_) + idx] =
        make_float4(v.x * rfin, v.y * rfin, v.z * rfin, v.w * rfin);
  }
}

extern "C" void kernel_launch(void* const* d_in, const int* in_sizes, int n_in,
                              void* d_out, int out_size, void* d_ws, size_t ws_size,
                              hipStream_t stream) {
  const float* x    = (const float*)d_in[0];   // [32,128,64,64] fp32
  const float* cent = (const float*)d_in[1];   // [64,128] fp32
  float* out = (float*)d_out;                  // [32, 8192] fp32

  float* vlad_part = (float*)d_ws;                                     // 32*16*8192
  float* asum_part = vlad_part + (size_t)N_ * NCHUNK * K_ * C_;        // 32*16*64
  float* vlad_n    = asum_part + (size_t)N_ * NCHUNK * K_;             // 32*8192
  float* rssq      = vlad_n + (size_t)N_ * K_ * C_;                    // 32*64

  dim3 g1(NCHUNK, N_);
  nv_stage1<<<g1, NT, 0, stream>>>(x, cent, vlad_part, asum_part);
  nv_stage2a<<<N_ * 8, 256, 0, stream>>>(vlad_part, asum_part, cent, vlad_n, rssq);
  nv_stage2b<<<N_, 256, 0, stream>>>(vlad_n, rssq, out);
}

// Round 10
// 47.472 us; speedup vs baseline: 1.3510x; 1.3510x over previous
//
#include <hip/hip_runtime.h>
#include <math.h>

#define ALPHA_F 100.0f

constexpr int N_ = 32, C_ = 128, K_ = 64, S_ = 4096;
constexpr int NCHUNK = 16, SCHUNK = S_ / NCHUNK;  // 256
constexpr int ST = 64, NSUB = SCHUNK / ST;        // 4 subtiles of 64 pixels
constexpr int NT = 256;                           // 4 waves, 2 blocks/CU

typedef _Float16 f16;
typedef __attribute__((ext_vector_type(4))) _Float16 f16x4;
typedef __attribute__((ext_vector_type(8))) _Float16 f16x8;
typedef __attribute__((ext_vector_type(4))) float f32x4;

// LDS (bytes), 40 KiB/block -> 2 blocks/CU with big margin.
// xbh: x fp16 [c=128][s=64]; a_s: a' fp16 [k=64][s=64]; cls: cent-lo [64][128].
// Swizzle helpers below are the ONLY place addresses are formed (writer==reader).
constexpr int XBH = 0;        // 16384
constexpr int ASB = 16384;    // 8192  (f32 scr alias pre-loop)
constexpr int CLS = 24576;    // 16384
constexpr int LDS_SZ = 40960;
// epilogue reuse: vst f32 [64][132] at 0 (33792), asum scr2 at 34816 (1024)

__device__ __forceinline__ int xaddr(int c, int s) {   // u16 index into xbh
  int oct = s >> 3;
  int swz = oct ^ (c & 7) ^ ((c >> 3) & 3);
  return c * 64 + (swz << 3) + (s & 7);
}
__device__ __forceinline__ int aaddr(int k, int s) {   // u16 index into a_s
  int oct = s >> 3;
  int swz = oct ^ (k & 7) ^ ((k >> 3) & 3);
  return k * 64 + (swz << 3) + (s & 7);
}
__device__ __forceinline__ int caddr(int k, int c) {   // u16 index into cls
  int oct = c >> 3;
  int swz = oct ^ (k & 15);
  return k * 128 + (swz << 3) + (c & 7);
}

#define BARRIER() do { asm volatile("s_waitcnt lgkmcnt(0)" ::: "memory"); \
                       __builtin_amdgcn_s_barrier(); } while (0)

__global__ __launch_bounds__(NT, 2)
void nv_stage1(const float* __restrict__ x, const float* __restrict__ cent,
               float* __restrict__ vlad_part, float* __restrict__ asum_part) {
  __shared__ __align__(16) unsigned char lds[LDS_SZ];
  ushort* xbh = (ushort*)(lds + XBH);
  ushort* a_s = (ushort*)(lds + ASB);
  float*  scr = (float*)(lds + ASB);
  ushort* cls = (ushort*)(lds + CLS);

  const int t = threadIdx.x;
  const int l = t & 63, w = t >> 6;            // 4 waves
  const int l16 = l & 15, g = l >> 4;
  const int chunk = blockIdx.x, n = blockIdx.y;
  const int sb = w * 16;                       // wave's 16-pixel GEMM1 tile

  const float* xg = x + (size_t)n * C_ * S_ + (size_t)chunk * SCHUNK;
  const float* xcol0 = xg + sb + l16;          // lane's pixel column

  // ---- prologue: stage subtile 0 as hi/lo A-fragments (x read ONCE)
  f16x8 ah[4], al[4];
  float inv_cur;
  {
    float ss = 0.f;
    #pragma unroll
    for (int ks = 0; ks < 4; ++ks) {
      const float* p = xcol0 + (size_t)(ks * 32 + g * 8) * S_;
      #pragma unroll
      for (int j = 0; j < 8; ++j) {
        float v = p[(size_t)j * S_];
        ss += v * v;
        f16 h = (f16)v;
        ah[ks][j] = h;
        al[ks][j] = (f16)(v - (float)h);
      }
    }
    ss += __shfl_xor(ss, 16);
    ss += __shfl_xor(ss, 32);
    inv_cur = 1.0f / fmaxf(sqrtf(ss), 1e-12f);
  }

  // bias partials (k = l, c-range w*32..+32) -> scr[0..255]
  {
    const float* cr = cent + l * C_ + w * 32;
    float ss = 0.f;
    #pragma unroll
    for (int h = 0; h < 8; ++h) {
      float4 v = *(const float4*)(cr + h * 4);
      ss += v.x * v.x + v.y * v.y + v.z * v.z + v.w * v.w;
    }
    scr[w * 64 + l] = ss;
  }
  // cent-lo -> cls: thread covers row k = t>>2, octets (t&3)*4 .. +4
  {
    const int k = t >> 2;
    const float* cr = cent + k * C_;
    #pragma unroll
    for (int m = 0; m < 4; ++m) {
      int o = (t & 3) * 4 + m, c0 = o * 8;
      f16x8 lo;
      #pragma unroll
      for (int h = 0; h < 8; ++h) {
        float v = cr[c0 + h];
        lo[h] = (f16)(v - (float)((f16)v));
      }
      *(f16x8*)&cls[caddr(k, c0)] = lo;
    }
  }
  // cent-hi ALL rows in registers: chf[nt2][ks] (R3-validated layout)
  f16x8 chf[4][4];
  #pragma unroll
  for (int nt2 = 0; nt2 < 4; ++nt2)
    #pragma unroll
    for (int ks = 0; ks < 4; ++ks) {
      const float* cr = cent + (nt2 * 16 + l16) * C_ + ks * 32 + g * 8;
      float4 a4 = *(const float4*)cr, b4 = *(const float4*)(cr + 4);
      chf[nt2][ks][0] = (f16)a4.x; chf[nt2][ks][1] = (f16)a4.y;
      chf[nt2][ks][2] = (f16)a4.z; chf[nt2][ks][3] = (f16)a4.w;
      chf[nt2][ks][4] = (f16)b4.x; chf[nt2][ks][5] = (f16)b4.y;
      chf[nt2][ks][6] = (f16)b4.z; chf[nt2][ks][7] = (f16)b4.w;
    }
  __syncthreads();
  if (t < 64) {
    float ss = scr[t] + scr[64 + t] + scr[128 + t] + scr[192 + t];
    scr[256 + t] = -ALPHA_F * sqrtf(ss);       // bias, transient
  }
  __syncthreads();
  float bias_r[4];
  #pragma unroll
  for (int nt2 = 0; nt2 < 4; ++nt2) bias_r[nt2] = scr[256 + nt2 * 16 + l16];
  __syncthreads();   // bias reads complete before a_s region is overwritten

  f32x4 acc2[2][4];
  #pragma unroll
  for (int cq2 = 0; cq2 < 2; ++cq2)
    #pragma unroll
    for (int nt2 = 0; nt2 < 4; ++nt2) { f32x4 z = {0.f,0.f,0.f,0.f}; acc2[cq2][nt2] = z; }
  float asum_acc[4] = {0.f, 0.f, 0.f, 0.f};

  for (int st = 0; st < NSUB; ++st) {
    // ---- P0: write xbh [c][s] from A-frag regs (swizzled scalar u16)
    {
      const int sP = sb + l16;
      union { f16x8 v; ushort u[8]; } cv;
      #pragma unroll
      for (int ks = 0; ks < 4; ++ks) {
        cv.v = ah[ks];
        #pragma unroll
        for (int j = 0; j < 8; ++j) {
          int c = ks * 32 + g * 8 + j;
          xbh[xaddr(c, sP)] = cv.u[j];
        }
      }
    }

    // ---- D: GEMM1 (ah*bh + ah*bl + al*bh); softmax; a' -> a_s
    {
      f32x4 acc1[4];
      #pragma unroll
      for (int nt2 = 0; nt2 < 4; ++nt2) { f32x4 z = {0.f,0.f,0.f,0.f}; acc1[nt2] = z; }
      #pragma unroll
      for (int ks = 0; ks < 4; ++ks) {
        #pragma unroll
        for (int nt2 = 0; nt2 < 4; ++nt2) {
          f16x8 bh = chf[nt2][ks];
          f16x8 bl = *(const f16x8*)&cls[caddr(nt2 * 16 + l16, ks * 32 + g * 8)];
          acc1[nt2] = __builtin_amdgcn_mfma_f32_16x16x32_f16(ah[ks], bh, acc1[nt2], 0, 0, 0);
          acc1[nt2] = __builtin_amdgcn_mfma_f32_16x16x32_f16(ah[ks], bl, acc1[nt2], 0, 0, 0);
          acc1[nt2] = __builtin_amdgcn_mfma_f32_16x16x32_f16(al[ks], bh, acc1[nt2], 0, 0, 0);
        }
      }
      float inv4[4];
      #pragma unroll
      for (int i = 0; i < 4; ++i) inv4[i] = __shfl(inv_cur, 4 * g + i, 64);
      float v[4][4], mx[4], sm[4];
      #pragma unroll
      for (int nt2 = 0; nt2 < 4; ++nt2)
        #pragma unroll
        for (int i = 0; i < 4; ++i)
          v[nt2][i] = 2.f * ALPHA_F * acc1[nt2][i] * inv4[i] + bias_r[nt2];
      #pragma unroll
      for (int i = 0; i < 4; ++i) {
        mx[i] = fmaxf(fmaxf(v[0][i], v[1][i]), fmaxf(v[2][i], v[3][i]));
        mx[i] = fmaxf(mx[i], __shfl_xor(mx[i], 1));
        mx[i] = fmaxf(mx[i], __shfl_xor(mx[i], 2));
        mx[i] = fmaxf(mx[i], __shfl_xor(mx[i], 4));
        mx[i] = fmaxf(mx[i], __shfl_xor(mx[i], 8));
        sm[i] = 0.f;
      }
      #pragma unroll
      for (int nt2 = 0; nt2 < 4; ++nt2)
        #pragma unroll
        for (int i = 0; i < 4; ++i) { float e = __expf(v[nt2][i] - mx[i]); v[nt2][i] = e; sm[i] += e; }
      #pragma unroll
      for (int i = 0; i < 4; ++i) {
        sm[i] += __shfl_xor(sm[i], 1); sm[i] += __shfl_xor(sm[i], 2);
        sm[i] += __shfl_xor(sm[i], 4); sm[i] += __shfl_xor(sm[i], 8);
        sm[i] = 1.0f / sm[i];
      }
      // a' write: k = nt2*16+l16, pixels s = sb + 4g + i (f16x4 at s&7 = (g&1)*4)
      const int s0 = sb + 4 * (g & ~1) * 2;  // unused; keep simple below
      #pragma unroll
      for (int nt2 = 0; nt2 < 4; ++nt2) {
        float a0 = v[nt2][0] * sm[0], a1 = v[nt2][1] * sm[1];
        float a2 = v[nt2][2] * sm[2], a3 = v[nt2][3] * sm[3];
        asum_acc[nt2] += a0 + a1 + a2 + a3;
        f16x4 av;
        av[0] = (f16)(a0 * inv4[0]); av[1] = (f16)(a1 * inv4[1]);
        av[2] = (f16)(a2 * inv4[2]); av[3] = (f16)(a3 * inv4[3]);
        *(f16x4*)&a_s[aaddr(nt2 * 16 + l16, sb + 4 * g)] = av;
      }
    }
    BARRIER();  // xbh + a_s ready for all waves

    // ---- E: GEMM2 D[c][k] += x[c][s] . a'[k][s]; 2 c-tiles/wave, kss over s
    #pragma unroll
    for (int cq2 = 0; cq2 < 2; ++cq2) {
      const int c = cq2 * 64 + w * 16 + l16;
      #pragma unroll
      for (int kss = 0; kss < 2; ++kss) {
        f16x8 xu = *(const f16x8*)&xbh[xaddr(c, kss * 32 + g * 8)];
        #pragma unroll
        for (int nt2 = 0; nt2 < 4; ++nt2) {
          f16x8 pa = *(const f16x8*)&a_s[aaddr(nt2 * 16 + l16, kss * 32 + g * 8)];
          acc2[cq2][nt2] = __builtin_amdgcn_mfma_f32_16x16x32_f16(xu, pa, acc2[cq2][nt2], 0, 0, 0);
        }
      }
    }
    // prefetch next subtile hi/lo A-frags (overlaps MFMA drain)
    if (st + 1 < NSUB) {
      const float* xc = xcol0 + (st + 1) * ST;
      float ss = 0.f;
      #pragma unroll
      for (int ks = 0; ks < 4; ++ks) {
        const float* p = xc + (size_t)(ks * 32 + g * 8) * S_;
        #pragma unroll
        for (int j = 0; j < 8; ++j) {
          float v = p[(size_t)j * S_];
          ss += v * v;
          f16 h = (f16)v;
          ah[ks][j] = h;
          al[ks][j] = (f16)(v - (float)h);
        }
      }
      ss += __shfl_xor(ss, 16);
      ss += __shfl_xor(ss, 32);
      inv_cur = 1.0f / fmaxf(sqrtf(ss), 1e-12f);
    }
    BARRIER();  // xbh/a_s consumed; safe to overwrite next iteration
  }

  // ---- epilogue: stage acc2 (k = nt2*16+l16, c = cq2*64 + w*16 + 4g+i) + asum
  {
    float* vst  = (float*)(lds + 0);        // f32 [64][132] = 33792 B
    float* scr2 = (float*)(lds + 34816);    // f32 [256]
    #pragma unroll
    for (int cq2 = 0; cq2 < 2; ++cq2)
      #pragma unroll
      for (int nt2 = 0; nt2 < 4; ++nt2) {
        const int k = nt2 * 16 + l16, q = cq2 * 16 + w * 4 + g;
        float4 o = make_float4(acc2[cq2][nt2][0], acc2[cq2][nt2][1],
                               acc2[cq2][nt2][2], acc2[cq2][nt2][3]);
        *(float4*)&vst[k * 132 + q * 4] = o;
      }
    #pragma unroll
    for (int nt2 = 0; nt2 < 4; ++nt2) {
      float vv = asum_acc[nt2];
      vv += __shfl_xor(vv, 16); vv += __shfl_xor(vv, 32);
      if (g == 0) scr2[w * 64 + nt2 * 16 + l16] = vv;
    }
    BARRIER();
    const size_t base = (size_t)(n * NCHUNK + chunk) * (K_ * C_);
    #pragma unroll
    for (int it = 0; it < 8; ++it) {
      int f = t + it * 256;                  // float4 slot in [0,2048)
      int k = f >> 5, q = f & 31;
      float4 v = *(float4*)&vst[k * 132 + q * 4];
      *(float4*)&vlad_part[base + (size_t)k * C_ + q * 4] = v;  // contiguous
    }
    if (t < 64) {
      float s2 = scr2[t] + scr2[64 + t] + scr2[128 + t] + scr2[192 + t];
      asum_part[(n * NCHUNK + chunk) * K_ + t] = s2;
    }
  }
}

// ---- stage 2a: reduce chunks, subtract, intra-normalize (256 blocks) ----
__global__ __launch_bounds__(256)
void nv_stage2a(const float* __restrict__ vlad_part, const float* __restrict__ asum_part,
                const float* __restrict__ cent, float* __restrict__ vlad_n,
                float* __restrict__ rssq) {
  const int t = threadIdx.x, b = blockIdx.x;
  const int n = b >> 3, k8 = (b & 7) * 8;
  const int kl = t >> 5, c4 = (t & 31) * 4;
  const int k = k8 + kl;
  float as = 0.f;
  for (int ch = 0; ch < NCHUNK; ++ch) as += asum_part[(n * NCHUNK + ch) * K_ + k];
  float4 acc = make_float4(0.f, 0.f, 0.f, 0.f);
  for (int ch = 0; ch < NCHUNK; ++ch) {
    float4 v = *(const float4*)&vlad_part[((size_t)(n * NCHUNK + ch) * K_ + k) * C_ + c4];
    acc.x += v.x; acc.y += v.y; acc.z += v.z; acc.w += v.w;
  }
  float4 cw = *(const float4*)&cent[k * C_ + c4];
  acc.x -= as * cw.x; acc.y -= as * cw.y; acc.z -= as * cw.z; acc.w -= as * cw.w;
  float ssq = acc.x * acc.x + acc.y * acc.y + acc.z * acc.z + acc.w * acc.w;
  #pragma unroll
  for (int m = 1; m <= 16; m <<= 1) ssq += __shfl_xor(ssq, m);
  float scl = 1.0f / fmaxf(sqrtf(ssq), 1e-12f);
  *(float4*)&vlad_n[(size_t)n * (K_ * C_) + k * C_ + c4] =
      make_float4(acc.x * scl, acc.y * scl, acc.z * scl, acc.w * scl);
  if ((t & 31) == 0) rssq[n * K_ + k] = ssq * scl * scl;
}

// ---- stage 2b: global L2 normalize (32 blocks) ----
__global__ __launch_bounds__(256)
void nv_stage2b(const float* __restrict__ vlad_n, const float* __restrict__ rssq,
                float* __restrict__ out) {
  const int t = threadIdx.x, n = blockIdx.x;
  float tot = 0.f;
  for (int k2 = 0; k2 < K_; ++k2) tot += rssq[n * K_ + k2];
  const float rfin = 1.0f / fmaxf(sqrtf(tot), 1e-12f);
  #pragma unroll
  for (int r = 0; r < 8; ++r) {
    int idx = t * 4 + r * 1024;
    float4 v = *(const float4*)&vlad_n[(size_t)n * (K_ * C_) + idx];
    *(float4*)&out[(size_t)n * (K_ * C_) + idx] =
        make_float4(v.x * rfin, v.y * rfin, v.z * rfin, v.w * rfin);
  }
}

extern "C" void kernel_launch(void* const* d_in, const int* in_sizes, int n_in,
                              void* d_out, int out_size, void* d_ws, size_t ws_size,
                              hipStream_t stream) {
  const float* x    = (const float*)d_in[0];   // [32,128,64,64] fp32
  const float* cent = (const float*)d_in[1];   // [64,128] fp32
  float* out = (float*)d_out;                  // [32, 8192] fp32

  float* vlad_part = (float*)d_ws;                                     // 32*16*8192
  float* asum_part = vlad_part + (size_t)N_ * NCHUNK * K_ * C_;        // 32*16*64
  float* vlad_n    = asum_part + (size_t)N_ * NCHUNK * K_;             // 32*8192
  float* rssq      = vlad_n + (size_t)N_ * K_ * C_;                    // 32*64

  dim3 g1(NCHUNK, N_);
  nv_stage1<<<g1, NT, 0, stream>>>(x, cent, vlad_part, asum_part);
  nv_stage2a<<<N_ * 8, 256, 0, stream>>>(vlad_part, asum_part, cent, vlad_n, rssq);
  nv_stage2b<<<N_, 256, 0, stream>>>(vlad_n, rssq, out);
}